// Round 5
// baseline (3774.557 us; speedup 1.0000x reference)
//
#include <hip/hip_runtime.h>
#include <stdint.h>

#define HID 512

typedef __attribute__((ext_vector_type(8))) short bf16x8;
typedef __attribute__((ext_vector_type(8))) short short8v;
typedef __attribute__((ext_vector_type(4))) float f32x4;

#define WAITB(N) asm volatile("s_waitcnt vmcnt(" #N ")" ::: "memory")

__device__ __forceinline__ unsigned short f2bf_rne(float f) {
  unsigned u = __float_as_uint(f);
  unsigned r = u + 0x7fffu + ((u >> 16) & 1u);
  return (unsigned short)(r >> 16);
}
__device__ __forceinline__ float bf2f(unsigned short u) {
  return __uint_as_float(((unsigned)u) << 16);
}

__device__ __forceinline__ void gload_lds16(const void* g, void* l) {
  auto gp = reinterpret_cast<const __attribute__((address_space(1))) unsigned int*>(
      (unsigned long long)(uintptr_t)g);
  auto lp = reinterpret_cast<__attribute__((address_space(3))) unsigned int*>(
      (unsigned int)(uintptr_t)l);
  __builtin_amdgcn_global_load_lds(gp, lp, 16, 0, 0);
}

// W [512 k][512 n] -> Bp [n][1024] = [hi(W[k][n]) | lo(W[k][n])]
__global__ void pack_main(const float* __restrict__ W, short* __restrict__ Bp) {
  int id = blockIdx.x * 256 + threadIdx.x;   // 512*1024
  int n = id >> 10, kk = id & 1023, k = kk & 511;
  float w = W[(size_t)k * 512 + n];
  unsigned short h = f2bf_rne(w);
  Bp[id] = (kk < 512) ? (short)h : (short)f2bf_rne(w - bf2f(h));
}

// P1w [1024 k][512 n] -> Pp [n][2048] = [hi(top) | hi(bot) | lo(top) | lo(bot)]
__global__ void pack_p1(const float* __restrict__ P1, short* __restrict__ Pp) {
  int id = blockIdx.x * 256 + threadIdx.x;   // 512*2048
  int n = id >> 11, kk = id & 2047;
  int s2 = kk >> 9, k2 = kk & 511;
  float w = P1[(size_t)((s2 & 1) * 512 + k2) * 512 + n];
  unsigned short h = f2bf_rne(w);
  Pp[id] = (s2 < 2) ? (short)h : (short)f2bf_rne(w - bf2f(h));
}

__global__ void split_x_kernel(const float* __restrict__ x, short* __restrict__ hi,
                               short* __restrict__ lo, int n8) {
  int id = blockIdx.x * 256 + threadIdx.x;
  if (id >= n8) return;
  const f32x4* xp = reinterpret_cast<const f32x4*>(x) + (size_t)id * 2;
  f32x4 a = xp[0], b = xp[1];
  short8v h, l;
#pragma unroll
  for (int q = 0; q < 4; ++q) {
    unsigned short ha = f2bf_rne(a[q]);
    h[q] = (short)ha; l[q] = (short)f2bf_rne(a[q] - bf2f(ha));
    unsigned short hb = f2bf_rne(b[q]);
    h[q + 4] = (short)hb; l[q + 4] = (short)f2bf_rne(b[q] - bf2f(hb));
  }
  reinterpret_cast<short8v*>(hi)[id] = h;
  reinterpret_cast<short8v*>(lo)[id] = l;
}

__global__ void init_out_kernel(float* __restrict__ out, const float* __restrict__ p3b, int n) {
  int id = blockIdx.x * 256 + threadIdx.x;
  if (id < n) out[id] = p3b[0];
}

// 8-phase 256x256 bf16 GEMM over folded K' (split precision via K-segments).
// EPI: 0 = C = relu(acc+bias) -> hi/lo planes
//      1 = C = relu(acc+bias) + (Ahi+Alo) -> hi/lo planes  (residual)
//      2 = score[row] += dot(relu(acc+bias), p3)           (fused projection)
// GATHER: A rows gathered via isrc/idst with 6-segment K' (Z-build GEMM)
template <int EPI, bool GATHER, int NT>
__global__ __launch_bounds__(512, 2) void gemm8(
    const short* __restrict__ Ahi, const short* __restrict__ Alo,
    const short* __restrict__ Bp,
    const float* __restrict__ bias, const float* __restrict__ p3,
    const int* __restrict__ isrc, const int* __restrict__ idst,
    short* __restrict__ Chi, short* __restrict__ Clo,
    float* __restrict__ score, int M) {
  constexpr int BPW = GATHER ? 2048 : 1024;

  __shared__ __align__(16) short lds[2][32768];   // per buf: A 16384 shorts, B 16384

  const int tid = threadIdx.x;
  const int lane = tid & 63;
  const int wid = tid >> 6;
  const int wr = wid >> 2, wc = wid & 3;      // 2x4 waves; per-wave 128 rows x 64 cols
  const int l15 = lane & 15, lh = lane >> 4;

  // XCD-paired swizzle: the two x-blocks of a y-tile land on the same XCD
  const int yb = (M + 255) >> 8;
  const int px = (yb + 7) >> 3;
  const int g = blockIdx.x;
  const int c8 = g & 7, idx = g >> 3;
  const int xblk = idx & 1, y = c8 * px + (idx >> 1);
  if (y >= yb) return;
  const int m0 = y << 8;
  const int n0 = xblk << 8;

  // ---- staging identity: thread t owns row (t&255), slab-half (t>>8) ----
  const int arow = tid & 255;
  const int tHi = tid >> 8;
  int grow = m0 + arow; if (grow > M - 1) grow = M - 1;
  size_t offS, offD = 0;
  if constexpr (GATHER) {
    offS = (size_t)isrc[grow] * HID;
    offD = (size_t)idst[grow] * HID;
  } else {
    offS = (size_t)grow * HID;
  }
  const size_t bRow = (size_t)(n0 + arow) * BPW;

  // per-tile A source base / B k'-offset (segment mapping of the K-folding)
  auto aSrc = [&](int kt) -> const short* {
    int seg = kt >> 3, k2 = (kt & 7) << 6;
    if constexpr (!GATHER) {
      const short* pl = (seg == 1) ? Alo : Ahi;     // [hi | lo | hi]
      return pl + offS + k2;
    } else {
      const short* pl = (seg == 2 || seg == 3) ? Alo : Ahi;  // [hiS hiD loS loD hiS hiD]
      size_t off = (seg & 1) ? offD : offS;
      return pl + off + k2;
    }
  };
  auto bOff = [&](int kt) -> int {
    int seg = kt >> 3, k2 = (kt & 7) << 6;
    if constexpr (!GATHER) return ((seg == 2) ? 512 : 0) + k2;       // [Whi | Whi | Wlo]
    else return ((seg >= 4) ? 1024 : 0) + ((seg & 1) << 9) + k2;     // Pp quadrants
  };
  auto stageA = [&](short* buf, const short* ab, int c) {
    gload_lds16(ab + (2 * c + tHi) * 8, buf + c * 4096 + tid * 8);
  };
  auto stageB = [&](short* buf, int bo, int c) {
    gload_lds16(Bp + bRow + bo + (2 * c + tHi) * 8, buf + 16384 + c * 4096 + tid * 8);
  };

  f32x4 acc[8][4];
#pragma unroll
  for (int i = 0; i < 8; ++i)
#pragma unroll
    for (int j = 0; j < 4; ++j)
#pragma unroll
      for (int r = 0; r < 4; ++r) acc[i][j][r] = 0.f;

  // LDS layout: slab s = k_local/8 (0..7): [s][256 rows][8 shorts] -> fully
  // contiguous 16B/lane on both DMA write and frag read (conflict-free).
  auto rdA = [&](const short* buf, int k32, int half, bf16x8* fr) {
#pragma unroll
    for (int q = 0; q < 4; ++q) {
      int fi = half * 4 + q;
      fr[q] = *reinterpret_cast<const bf16x8*>(
          buf + (k32 * 4 + lh) * 2048 + (wr * 128 + fi * 16 + l15) * 8);
    }
  };
  auto rdB = [&](const short* buf, int k32, bf16x8* fr) {
#pragma unroll
    for (int q = 0; q < 4; ++q)
      fr[q] = *reinterpret_cast<const bf16x8*>(
          buf + 16384 + (k32 * 4 + lh) * 2048 + (wc * 64 + q * 16 + l15) * 8);
  };
  auto mm16 = [&](const bf16x8* afr, const bf16x8* bfr, int half) {
    __builtin_amdgcn_s_setprio(1);
#pragma unroll
    for (int fj = 0; fj < 4; ++fj)
#pragma unroll
      for (int q = 0; q < 4; ++q)
        acc[half * 4 + q][fj] = __builtin_amdgcn_mfma_f32_16x16x32_bf16(
            afr[q], bfr[fj], acc[half * 4 + q][fj], 0, 0, 0);
    __builtin_amdgcn_s_setprio(0);
  };

  // ---- prologue: stage tile 0 (order: k32=0 rounds first), counted wait ----
  {
    const short* ab = aSrc(0); const int bo = bOff(0);
    stageA(lds[0], ab, 0); stageB(lds[0], bo, 0);
    stageA(lds[0], ab, 1); stageB(lds[0], bo, 1);
    stageA(lds[0], ab, 2); stageB(lds[0], bo, 2);
    stageA(lds[0], ab, 3); stageB(lds[0], bo, 3);
  }
  WAITB(4);
  __builtin_amdgcn_s_barrier();
  __builtin_amdgcn_sched_barrier(0);

  // ---- main loop: 4 phases/tile, vmcnt(4) only at q1/q3 ----
  for (int kt = 0; kt < NT; ++kt) {
    short* cur = lds[kt & 1];
    short* nxt = lds[(kt & 1) ^ 1];
    const bool st = (kt + 1 < NT);
    const short* ab = st ? aSrc(kt + 1) : Ahi;
    const int bo = st ? bOff(kt + 1) : 0;
    bf16x8 afr[4], bfr[4];

    // q0: k32=0, fi 0-3
    rdB(cur, 0, bfr); rdA(cur, 0, 0, afr);
    if (st) { stageA(nxt, ab, 0); stageB(nxt, bo, 0); }
    __builtin_amdgcn_s_barrier();
    mm16(afr, bfr, 0);
    __builtin_amdgcn_s_barrier();
    __builtin_amdgcn_sched_barrier(0);

    // q1: k32=0, fi 4-7
    rdA(cur, 0, 1, afr);
    if (st) { stageA(nxt, ab, 1); stageB(nxt, bo, 1); }
    __builtin_amdgcn_s_barrier();
    mm16(afr, bfr, 1);
    if (st) { WAITB(4); } else { WAITB(0); }   // own k32=1 landed
    __builtin_amdgcn_s_barrier();
    __builtin_amdgcn_sched_barrier(0);

    // q2: k32=1, fi 0-3
    rdB(cur, 1, bfr); rdA(cur, 1, 0, afr);
    if (st) { stageA(nxt, ab, 2); stageB(nxt, bo, 2); }
    __builtin_amdgcn_s_barrier();
    mm16(afr, bfr, 0);
    __builtin_amdgcn_s_barrier();
    __builtin_amdgcn_sched_barrier(0);

    // q3: k32=1, fi 4-7
    rdA(cur, 1, 1, afr);
    if (st) { stageA(nxt, ab, 3); stageB(nxt, bo, 3); }
    __builtin_amdgcn_s_barrier();
    mm16(afr, bfr, 1);
    if (st) { WAITB(4); }                      // next tile's k32=0 landed
    __builtin_amdgcn_s_barrier();
    __builtin_amdgcn_sched_barrier(0);
  }

  // ---- epilogue ----
  const int colB = n0 + wc * 64;
  if constexpr (EPI == 2) {
    float bj[4], pj[4];
#pragma unroll
    for (int fj = 0; fj < 4; ++fj) {
      int c = colB + fj * 16 + l15;
      bj[fj] = bias[c]; pj[fj] = p3[c];
    }
#pragma unroll
    for (int fi = 0; fi < 8; ++fi)
#pragma unroll
      for (int r = 0; r < 4; ++r) {
        float pS = 0.f;
#pragma unroll
        for (int fj = 0; fj < 4; ++fj)
          pS += fmaxf(acc[fi][fj][r] + bj[fj], 0.f) * pj[fj];
        pS += __shfl_xor(pS, 1);
        pS += __shfl_xor(pS, 2);
        pS += __shfl_xor(pS, 4);
        pS += __shfl_xor(pS, 8);
        int row = m0 + wr * 128 + fi * 16 + lh * 4 + r;
        if (l15 == 0 && row < M) atomicAdd(&score[row], pS);
      }
  } else {
    float bj[4];
#pragma unroll
    for (int fj = 0; fj < 4; ++fj) bj[fj] = bias[colB + fj * 16 + l15];
#pragma unroll
    for (int fi = 0; fi < 8; ++fi)
#pragma unroll
      for (int fj = 0; fj < 4; ++fj) {
#pragma unroll
        for (int r = 0; r < 4; ++r) {
          int row = m0 + wr * 128 + fi * 16 + lh * 4 + r;
          if (row < M) {
            size_t o = (size_t)row * HID + colB + fj * 16 + l15;
            float v = fmaxf(acc[fi][fj][r] + bj[fj], 0.f);
            if constexpr (EPI == 1) v += bf2f((unsigned short)Ahi[o]) + bf2f((unsigned short)Alo[o]);
            unsigned short h = f2bf_rne(v);
            Chi[o] = (short)h;
            Clo[o] = (short)f2bf_rne(v - bf2f(h));
          }
        }
      }
  }
}

extern "C" void kernel_launch(void* const* d_in, const int* in_sizes, int n_in,
                              void* d_out, int out_size, void* d_ws, size_t ws_size,
                              hipStream_t stream) {
  (void)n_in; (void)out_size; (void)ws_size;
  const float* x      = (const float*)d_in[0];
  const int* pos_src  = (const int*)d_in[1];
  const int* pos_dst  = (const int*)d_in[2];
  const int* neg_src  = (const int*)d_in[3];
  const int* neg_dst  = (const int*)d_in[4];
  const float* W1 = (const float*)d_in[5];
  const float* b1 = (const float*)d_in[6];
  const float* W2 = (const float*)d_in[7];
  const float* b2 = (const float*)d_in[8];
  const float* Wo = (const float*)d_in[9];
  const float* bo = (const float*)d_in[10];
  const float* P1w = (const float*)d_in[11];
  const float* P1b = (const float*)d_in[12];
  const float* P2w = (const float*)d_in[13];
  const float* P2b = (const float*)d_in[14];
  const float* P3w = (const float*)d_in[15];
  const float* P3b = (const float*)d_in[16];

  const int NN = in_sizes[0] / HID;  // 100000
  const int E = in_sizes[1];         // 100000
  float* out = (float*)d_out;

  // ws layout: 2 activation buffers (hi+lo planes) + packed weights
  const size_t PL = (size_t)NN * HID;            // elems per plane
  short* wsS = (short*)d_ws;
  short* A0hi = wsS;            short* A0lo = A0hi + PL;
  short* A1hi = A0lo + PL;      short* A1lo = A1hi + PL;
  short* wp = A1lo + PL;
  short* Wp1  = wp; wp += 512 * 1024;
  short* Wp2  = wp; wp += 512 * 1024;
  short* Wpo  = wp; wp += 512 * 1024;
  short* WpP2 = wp; wp += 512 * 1024;
  short* Pp   = wp; wp += 512 * 2048;

  pack_main<<<2048, 256, 0, stream>>>(W1, Wp1);
  pack_main<<<2048, 256, 0, stream>>>(W2, Wp2);
  pack_main<<<2048, 256, 0, stream>>>(Wo, Wpo);
  pack_main<<<2048, 256, 0, stream>>>(P2w, WpP2);
  pack_p1<<<4096, 256, 0, stream>>>(P1w, Pp);
  split_x_kernel<<<(NN * 64 + 255) / 256, 256, 0, stream>>>(x, A0hi, A0lo, NN * 64);
  init_out_kernel<<<(2 * E + 255) / 256, 256, 0, stream>>>(out, P3b, 2 * E);

  const int yb = (NN + 255) / 256;
  const int px = (yb + 7) / 8;
  dim3 grd(8 * px * 2), blk(512);

  // encoder: h1 = relu(x@W1+b1); h2 = relu(h1@W2+b2)+h1; h = relu(h2@Wo+bo)+h2
  gemm8<0, false, 24><<<grd, blk, 0, stream>>>(A0hi, A0lo, Wp1, b1, nullptr, nullptr, nullptr, A1hi, A1lo, nullptr, NN);
  gemm8<1, false, 24><<<grd, blk, 0, stream>>>(A1hi, A1lo, Wp2, b2, nullptr, nullptr, nullptr, A0hi, A0lo, nullptr, NN);
  gemm8<1, false, 24><<<grd, blk, 0, stream>>>(A0hi, A0lo, Wpo, bo, nullptr, nullptr, nullptr, A1hi, A1lo, nullptr, NN);
  // H in A1 planes.

  // positive edges: Z = relu([H[s],H[d]]@P1+b) (gathered K'=3072); scores = relu(Z@P2+b)@P3+b3
  gemm8<0, true, 48><<<grd, blk, 0, stream>>>(A1hi, A1lo, Pp, P1b, nullptr, pos_src, pos_dst, A0hi, A0lo, nullptr, E);
  gemm8<2, false, 24><<<grd, blk, 0, stream>>>(A0hi, A0lo, WpP2, P2b, P3w, nullptr, nullptr, nullptr, nullptr, out, E);

  // negative edges
  gemm8<0, true, 48><<<grd, blk, 0, stream>>>(A1hi, A1lo, Pp, P1b, nullptr, neg_src, neg_dst, A0hi, A0lo, nullptr, E);
  gemm8<2, false, 24><<<grd, blk, 0, stream>>>(A0hi, A0lo, WpP2, P2b, P3w, nullptr, nullptr, nullptr, nullptr, out + E, E);
}

// Round 6
// 2512.265 us; speedup vs baseline: 1.5025x; 1.5025x over previous
//
#include <hip/hip_runtime.h>
#include <stdint.h>

#define HID 512

typedef __attribute__((ext_vector_type(8))) short bf16x8;
typedef __attribute__((ext_vector_type(8))) short short8v;
typedef __attribute__((ext_vector_type(4))) float f32x4;

#define WAITB(N) asm volatile("s_waitcnt vmcnt(" #N ")" ::: "memory")
#define WAITLG asm volatile("s_waitcnt lgkmcnt(0)" ::: "memory")

__device__ __forceinline__ unsigned short f2bf_rne(float f) {
  unsigned u = __float_as_uint(f);
  unsigned r = u + 0x7fffu + ((u >> 16) & 1u);
  return (unsigned short)(r >> 16);
}
__device__ __forceinline__ float bf2f(unsigned short u) {
  return __uint_as_float(((unsigned)u) << 16);
}

__device__ __forceinline__ void gload_lds16(const void* g, void* l) {
  auto gp = reinterpret_cast<const __attribute__((address_space(1))) unsigned int*>(
      (unsigned long long)(uintptr_t)g);
  auto lp = reinterpret_cast<__attribute__((address_space(3))) unsigned int*>(
      (unsigned int)(uintptr_t)l);
  __builtin_amdgcn_global_load_lds(gp, lp, 16, 0, 0);
}

// ---- weight pack kernels: emit the exact LDS tile image [xblk][NT][s][256][8]
// encoder/P2 mapping (NT=24, K'=1536): tiles 0-15 pair (A=hi): B = kt&1 ? Wlo : Whi
// at k2=(kt>>1)*64; tiles 16-23 (A=lo): B = Whi at k2=(kt-16)*64.
__global__ void pack_enc(const float* __restrict__ W, short* __restrict__ Bp) {
  int id = blockIdx.x * 256 + threadIdx.x;   // 2*24*16384
  int e = id & 7, r = (id >> 3) & 255, s = (id >> 11) & 7;
  int v = id >> 14;
  int kt = v % 24, xblk = v / 24;
  int kl = s * 8 + e;
  int k, useLo;
  if (kt < 16) { k = (kt >> 1) * 64 + kl; useLo = kt & 1; }
  else         { k = (kt - 16) * 64 + kl; useLo = 0; }
  float w = W[(size_t)k * 512 + xblk * 256 + r];
  unsigned short h = f2bf_rne(w);
  Bp[id] = useLo ? (short)f2bf_rne(w - bf2f(h)) : (short)h;
}

// gather/P1 mapping (NT=48, K'=3072):
// kt<16:  A=hiS, B=(kt&1?loT:hiT), k2=((kt>>1)&7)*64
// kt<32:  A=hiD, B=(kt&1?loB:hiB), k2 same
// kt>=32: A=(kt&1?loD:loS), B=hi(kt&1?B:T), k2=((kt-32)>>1)*64
__global__ void pack_gat(const float* __restrict__ P1, short* __restrict__ Bp) {
  int id = blockIdx.x * 256 + threadIdx.x;   // 2*48*16384
  int e = id & 7, r = (id >> 3) & 255, s = (id >> 11) & 7;
  int v = id >> 14;
  int kt = v % 48, xblk = v / 48;
  int kl = s * 8 + e;
  int row, useLo;
  if (kt < 32) {
    int k2 = ((kt >> 1) & 7) * 64;
    row = (kt < 16 ? 0 : 512) + k2 + kl;
    useLo = kt & 1;
  } else {
    int k2 = ((kt - 32) >> 1) * 64;
    row = ((kt & 1) ? 512 : 0) + k2 + kl;
    useLo = 0;
  }
  float w = P1[(size_t)row * 512 + xblk * 256 + r];
  unsigned short h = f2bf_rne(w);
  Bp[id] = useLo ? (short)f2bf_rne(w - bf2f(h)) : (short)h;
}

__global__ void split_x_kernel(const float* __restrict__ x, short* __restrict__ hi,
                               short* __restrict__ lo, int n8) {
  int id = blockIdx.x * 256 + threadIdx.x;
  if (id >= n8) return;
  const f32x4* xp = reinterpret_cast<const f32x4*>(x) + (size_t)id * 2;
  f32x4 a = xp[0], b = xp[1];
  short8v h, l;
#pragma unroll
  for (int q = 0; q < 4; ++q) {
    unsigned short ha = f2bf_rne(a[q]);
    h[q] = (short)ha; l[q] = (short)f2bf_rne(a[q] - bf2f(ha));
    unsigned short hb = f2bf_rne(b[q]);
    h[q + 4] = (short)hb; l[q + 4] = (short)f2bf_rne(b[q] - bf2f(hb));
  }
  reinterpret_cast<short8v*>(hi)[id] = h;
  reinterpret_cast<short8v*>(lo)[id] = l;
}

__global__ void init_out_kernel(float* __restrict__ out, const float* __restrict__ p3b, int n) {
  int id = blockIdx.x * 256 + threadIdx.x;
  if (id < n) out[id] = p3b[0];
}

// 8-phase 256x256 GEMM, split precision via K'-folding.
// EPI: 0 = relu(acc+bias) -> hi/lo planes; 1 = +residual; 2 = fused P3 dot -> score
template <int EPI, bool GATHER, int NT>
__global__ __launch_bounds__(512, 2) void gemm8(
    const short* __restrict__ Ahi, const short* __restrict__ Alo,
    const short* __restrict__ Bp,
    const float* __restrict__ bias, const float* __restrict__ p3,
    const int* __restrict__ isrc, const int* __restrict__ idst,
    short* __restrict__ Chi, short* __restrict__ Clo,
    float* __restrict__ score, int M) {
  __shared__ __align__(16) short lds[2][32768];   // per buf: A 16384, B 16384 shorts

  const int tid = threadIdx.x;
  const int lane = tid & 63;
  const int wid = tid >> 6;
  const int wr = wid >> 2, wc = wid & 3;          // 2x4 waves; 128 rows x 64 cols each
  const int l15 = lane & 15, lh = lane >> 4;

  // XCD-paired swizzle
  const int yb = (M + 255) >> 8;
  const int px = (yb + 7) >> 3;
  const int g = blockIdx.x;
  const int xblk = (g >> 3) & 1, y = (g & 7) * px + (g >> 4);
  if (y >= yb) return;
  const int m0 = y << 8;
  const int n0 = xblk << 8;

  const int arow = tid & 255;
  const int tHi = tid >> 8;
  int grow = m0 + arow; if (grow > M - 1) grow = M - 1;
  size_t offS, offD = 0;
  if constexpr (GATHER) {
    offS = (size_t)isrc[grow] * HID;
    offD = (size_t)idst[grow] * HID;
  } else {
    offS = (size_t)grow * HID;
  }

  // A source per tile (pair-reuse ordering; matches pack kernels)
  auto aSrc = [&](int kt) -> const short* {
    if constexpr (!GATHER) {
      if (kt < 16) return Ahi + offS + ((kt >> 1) << 6);
      return Alo + offS + ((kt - 16) << 6);
    } else {
      if (kt < 16) return Ahi + offS + (((kt >> 1) & 7) << 6);
      if (kt < 32) return Ahi + offD + (((kt >> 1) & 7) << 6);
      return Alo + ((kt & 1) ? offD : offS) + (((kt - 32) >> 1) << 6);
    }
  };
  // B stage: wave-contiguous 1KB DMA from the pre-packed tile image
  auto stageB1 = [&](int kt, short* buf, int c) {
    const short* src = Bp + ((size_t)xblk * NT + kt) * 16384 + c * 4096 + tid * 8;
    gload_lds16(src, buf + 16384 + c * 4096 + tid * 8);
  };
  auto ldA = [&](int kt, bf16x8* aR) {
    const short* ab = aSrc(kt) + tHi * 32;
#pragma unroll
    for (int q = 0; q < 4; ++q) aR[q] = *reinterpret_cast<const bf16x8*>(ab + q * 8);
  };
  auto wrA = [&](short* buf, const bf16x8* aR) {
#pragma unroll
    for (int q = 0; q < 4; ++q)
      *reinterpret_cast<bf16x8*>(buf + (tHi * 4 + q) * 2048 + arow * 8) = aR[q];
  };

  f32x4 acc[8][4];
#pragma unroll
  for (int i = 0; i < 8; ++i)
#pragma unroll
    for (int j = 0; j < 4; ++j)
#pragma unroll
      for (int r = 0; r < 4; ++r) acc[i][j][r] = 0.f;

  // LDS: [slab 0..7][256 rows][8 shorts] per operand — conflict-free both sides
  auto rdA = [&](const short* buf, int k32, int half, bf16x8* fr) {
#pragma unroll
    for (int q = 0; q < 4; ++q) {
      int fi = half * 4 + q;
      fr[q] = *reinterpret_cast<const bf16x8*>(
          buf + (k32 * 4 + lh) * 2048 + (wr * 128 + fi * 16 + l15) * 8);
    }
  };
  auto rdB = [&](const short* buf, int k32, bf16x8* fr) {
#pragma unroll
    for (int q = 0; q < 4; ++q)
      fr[q] = *reinterpret_cast<const bf16x8*>(
          buf + 16384 + (k32 * 4 + lh) * 2048 + (wc * 64 + q * 16 + l15) * 8);
  };
  auto mm16 = [&](const bf16x8* afr, const bf16x8* bfr, int half) {
    __builtin_amdgcn_s_setprio(1);
#pragma unroll
    for (int fj = 0; fj < 4; ++fj)
#pragma unroll
      for (int q = 0; q < 4; ++q)
        acc[half * 4 + q][fj] = __builtin_amdgcn_mfma_f32_16x16x32_bf16(
            afr[q], bfr[fj], acc[half * 4 + q][fj], 0, 0, 0);
    __builtin_amdgcn_s_setprio(0);
  };

  bf16x8 aR[4], afr[4], bfr[4];

  // ---- prologue: A(0)->regs, B(0) c0..c3 DMA; write A(0); drain; barrier ----
  ldA(0, aR);
  stageB1(0, lds[0], 0); stageB1(0, lds[0], 1);
  stageB1(0, lds[0], 2); stageB1(0, lds[0], 3);
  WAITB(4);                    // A regs landed (issued first)
  wrA(lds[0], aR);
  WAITB(0);                    // B tile 0 landed
  WAITLG;
  __builtin_amdgcn_s_barrier();
  __builtin_amdgcn_sched_barrier(0);

  // ---- main loop (tiles 0..NT-2), tail peeled ----
  for (int kt = 0; kt < NT - 1; ++kt) {
    short* cur = lds[kt & 1];
    short* nxt = lds[(kt & 1) ^ 1];

    // q0
    rdB(cur, 0, bfr); rdA(cur, 0, 0, afr);
    ldA(kt + 1, aR);
    stageB1(kt + 1, nxt, 0);
    __builtin_amdgcn_s_barrier();
    mm16(afr, bfr, 0);
    __builtin_amdgcn_s_barrier();
    __builtin_amdgcn_sched_barrier(0);

    // q1
    rdA(cur, 0, 1, afr);
    stageB1(kt + 1, nxt, 1);
    __builtin_amdgcn_s_barrier();
    mm16(afr, bfr, 1);
    WAITB(6);                  // prev tile's c2,c3 landed (cur k32=1 ready)
    __builtin_amdgcn_s_barrier();
    __builtin_amdgcn_sched_barrier(0);

    // q2
    rdB(cur, 1, bfr); rdA(cur, 1, 0, afr);
    stageB1(kt + 1, nxt, 2);
    __builtin_amdgcn_s_barrier();
    mm16(afr, bfr, 0);
    __builtin_amdgcn_s_barrier();
    __builtin_amdgcn_sched_barrier(0);

    // q3
    rdA(cur, 1, 1, afr);
    stageB1(kt + 1, nxt, 3);
    __builtin_amdgcn_s_barrier();
    mm16(afr, bfr, 1);
    WAITB(2);                  // A(kt+1) regs + nxt c0,c1 landed; c2,c3 in flight
    wrA(nxt, aR);
    WAITLG;
    __builtin_amdgcn_s_barrier();
    __builtin_amdgcn_sched_barrier(0);
  }

  // ---- tail tile NT-1 ----
  {
    short* cur = lds[(NT - 1) & 1];
    rdB(cur, 0, bfr); rdA(cur, 0, 0, afr);
    __builtin_amdgcn_s_barrier();
    mm16(afr, bfr, 0);
    __builtin_amdgcn_s_barrier();
    rdA(cur, 0, 1, afr);
    mm16(afr, bfr, 1);
    WAITB(0);                  // own c2,c3 landed
    __builtin_amdgcn_s_barrier();
    rdB(cur, 1, bfr); rdA(cur, 1, 0, afr);
    mm16(afr, bfr, 0);
    rdA(cur, 1, 1, afr);
    mm16(afr, bfr, 1);
  }

  // ---- epilogue ----
  const int colB = n0 + wc * 64;
  if constexpr (EPI == 2) {
    float bj[4], pj[4];
#pragma unroll
    for (int fj = 0; fj < 4; ++fj) {
      int c = colB + fj * 16 + l15;
      bj[fj] = bias[c]; pj[fj] = p3[c];
    }
#pragma unroll
    for (int fi = 0; fi < 8; ++fi)
#pragma unroll
      for (int r = 0; r < 4; ++r) {
        float pS = 0.f;
#pragma unroll
        for (int fj = 0; fj < 4; ++fj)
          pS += fmaxf(acc[fi][fj][r] + bj[fj], 0.f) * pj[fj];
        pS += __shfl_xor(pS, 1);
        pS += __shfl_xor(pS, 2);
        pS += __shfl_xor(pS, 4);
        pS += __shfl_xor(pS, 8);
        int row = m0 + wr * 128 + fi * 16 + lh * 4 + r;
        if (l15 == 0 && row < M) atomicAdd(&score[row], pS);
      }
  } else {
    float bj[4];
#pragma unroll
    for (int fj = 0; fj < 4; ++fj) bj[fj] = bias[colB + fj * 16 + l15];
#pragma unroll
    for (int fi = 0; fi < 8; ++fi)
#pragma unroll
      for (int fj = 0; fj < 4; ++fj) {
#pragma unroll
        for (int r = 0; r < 4; ++r) {
          int row = m0 + wr * 128 + fi * 16 + lh * 4 + r;
          if (row < M) {
            size_t o = (size_t)row * HID + colB + fj * 16 + l15;
            float v = fmaxf(acc[fi][fj][r] + bj[fj], 0.f);
            if constexpr (EPI == 1) v += bf2f((unsigned short)Ahi[o]) + bf2f((unsigned short)Alo[o]);
            unsigned short h = f2bf_rne(v);
            Chi[o] = (short)h;
            Clo[o] = (short)f2bf_rne(v - bf2f(h));
          }
        }
      }
  }
}

extern "C" void kernel_launch(void* const* d_in, const int* in_sizes, int n_in,
                              void* d_out, int out_size, void* d_ws, size_t ws_size,
                              hipStream_t stream) {
  (void)n_in; (void)out_size; (void)ws_size;
  const float* x      = (const float*)d_in[0];
  const int* pos_src  = (const int*)d_in[1];
  const int* pos_dst  = (const int*)d_in[2];
  const int* neg_src  = (const int*)d_in[3];
  const int* neg_dst  = (const int*)d_in[4];
  const float* W1 = (const float*)d_in[5];
  const float* b1 = (const float*)d_in[6];
  const float* W2 = (const float*)d_in[7];
  const float* b2 = (const float*)d_in[8];
  const float* Wo = (const float*)d_in[9];
  const float* bo = (const float*)d_in[10];
  const float* P1w = (const float*)d_in[11];
  const float* P1b = (const float*)d_in[12];
  const float* P2w = (const float*)d_in[13];
  const float* P2b = (const float*)d_in[14];
  const float* P3w = (const float*)d_in[15];
  const float* P3b = (const float*)d_in[16];

  const int NN = in_sizes[0] / HID;  // 100000
  const int E = in_sizes[1];         // 100000
  float* out = (float*)d_out;

  const size_t PL = (size_t)NN * HID;
  short* wsS = (short*)d_ws;
  short* A0hi = wsS;            short* A0lo = A0hi + PL;
  short* A1hi = A0lo + PL;      short* A1lo = A1hi + PL;
  short* wp = A1lo + PL;
  short* Wp1  = wp; wp += 2 * 24 * 16384;
  short* Wp2  = wp; wp += 2 * 24 * 16384;
  short* Wpo  = wp; wp += 2 * 24 * 16384;
  short* WpP2 = wp; wp += 2 * 24 * 16384;
  short* Pp   = wp; wp += 2 * 48 * 16384;

  pack_enc<<<3072, 256, 0, stream>>>(W1, Wp1);
  pack_enc<<<3072, 256, 0, stream>>>(W2, Wp2);
  pack_enc<<<3072, 256, 0, stream>>>(Wo, Wpo);
  pack_enc<<<3072, 256, 0, stream>>>(P2w, WpP2);
  pack_gat<<<6144, 256, 0, stream>>>(P1w, Pp);
  split_x_kernel<<<(NN * 64 + 255) / 256, 256, 0, stream>>>(x, A0hi, A0lo, NN * 64);
  init_out_kernel<<<(2 * E + 255) / 256, 256, 0, stream>>>(out, P3b, 2 * E);

  const int yb = (NN + 255) / 256;
  const int px = (yb + 7) / 8;
  dim3 grd(8 * px * 2), blk(512);

  // encoder
  gemm8<0, false, 24><<<grd, blk, 0, stream>>>(A0hi, A0lo, Wp1, b1, nullptr, nullptr, nullptr, A1hi, A1lo, nullptr, NN);
  gemm8<1, false, 24><<<grd, blk, 0, stream>>>(A1hi, A1lo, Wp2, b2, nullptr, nullptr, nullptr, A0hi, A0lo, nullptr, NN);
  gemm8<1, false, 24><<<grd, blk, 0, stream>>>(A0hi, A0lo, Wpo, bo, nullptr, nullptr, nullptr, A1hi, A1lo, nullptr, NN);
  // H in A1 planes.

  // positive edges: Z = relu([H[s],H[d]]@P1+b); scores = relu(Z@P2+b)@P3 + b3
  gemm8<0, true, 48><<<grd, blk, 0, stream>>>(A1hi, A1lo, Pp, P1b, nullptr, pos_src, pos_dst, A0hi, A0lo, nullptr, E);
  gemm8<2, false, 24><<<grd, blk, 0, stream>>>(A0hi, A0lo, WpP2, P2b, P3w, nullptr, nullptr, nullptr, nullptr, out, E);

  // negative edges
  gemm8<0, true, 48><<<grd, blk, 0, stream>>>(A1hi, A1lo, Pp, P1b, nullptr, neg_src, neg_dst, A0hi, A0lo, nullptr, E);
  gemm8<2, false, 24><<<grd, blk, 0, stream>>>(A0hi, A0lo, WpP2, P2b, P3w, nullptr, nullptr, nullptr, nullptr, out + E, E);
}

// Round 8
// 1640.302 us; speedup vs baseline: 2.3011x; 1.5316x over previous
//
#include <hip/hip_runtime.h>
#include <stdint.h>

#define HID 512

typedef short bf16x8 __attribute__((ext_vector_type(8)));
typedef short short8v __attribute__((ext_vector_type(8)));
typedef float f32x4 __attribute__((ext_vector_type(4)));

__device__ __forceinline__ unsigned short f2bf_rne(float f) {
  unsigned u = __float_as_uint(f);
  unsigned r = u + 0x7fffu + ((u >> 16) & 1u);
  return (unsigned short)(r >> 16);
}
__device__ __forceinline__ float bf2f(unsigned short u) {
  return __uint_as_float(((unsigned)u) << 16);
}

__device__ __forceinline__ void gload_lds16(const void* g, void* l) {
  auto gp = reinterpret_cast<const __attribute__((address_space(1))) unsigned int*>(
      (unsigned long long)(uintptr_t)g);
  auto lp = reinterpret_cast<__attribute__((address_space(3))) unsigned int*>(
      (unsigned int)(uintptr_t)l);
  __builtin_amdgcn_global_load_lds(gp, lp, 16, 0, 0);
}

// ---------------- pack kernels ----------------
// pack4: W [512 k][512 n] -> [xb4][kt16][pl2][s4][128 n][8 k]  (1 MB)
__global__ void pack4(const float* __restrict__ W, short* __restrict__ out) {
  int id = blockIdx.x * 256 + threadIdx.x;                 // 2^19
  int e = id & 7, r = (id >> 3) & 127, s = (id >> 10) & 3, pl = (id >> 12) & 1,
      kt = (id >> 13) & 15, xb = id >> 17;
  int k = kt * 32 + s * 8 + e, n = xb * 128 + r;
  float w = W[(size_t)k * 512 + n];
  unsigned short h = f2bf_rne(w);
  out[id] = pl ? (short)f2bf_rne(w - bf2f(h)) : (short)h;
}

// packW: P1 rows 512..1023 -> [kt16][pl2][s4][512 n][8 k]  (1 MB, full width)
__global__ void packW(const float* __restrict__ P1, short* __restrict__ out) {
  int id = blockIdx.x * 256 + threadIdx.x;                 // 2^19
  int e = id & 7, r = (id >> 3) & 511, s = (id >> 12) & 3, pl = (id >> 14) & 1,
      kt = id >> 15;
  int k = kt * 32 + s * 8 + e;
  float w = P1[(size_t)(512 + k) * 512 + r];
  unsigned short h = f2bf_rne(w);
  out[id] = pl ? (short)f2bf_rne(w - bf2f(h)) : (short)h;
}

// split x -> hi/lo tile image [rb][kt16][pl2][s4][128][8]
__global__ void split_x_img(const float* __restrict__ x, short* __restrict__ img,
                            int NN, int total) {
  int id = blockIdx.x * 256 + threadIdx.x;
  if (id >= total) return;
  int n = id >> 6, kc = id & 63;
  int ns = n < NN ? n : NN - 1;
  const f32x4* xp = reinterpret_cast<const f32x4*>(x + (size_t)ns * 512 + kc * 8);
  f32x4 a = xp[0], b = xp[1];
  short8v h, l;
#pragma unroll
  for (int q = 0; q < 4; ++q) {
    unsigned short ha = f2bf_rne(a[q]);
    h[q] = (short)ha; l[q] = (short)f2bf_rne(a[q] - bf2f(ha));
    unsigned short hb = f2bf_rne(b[q]);
    h[q + 4] = (short)hb; l[q + 4] = (short)f2bf_rne(b[q] - bf2f(hb));
  }
  size_t base = ((size_t)((n >> 7) * 16 + (kc >> 2)) * 2) * 4096 + (kc & 3) * 1024 + (n & 127) * 8;
  *reinterpret_cast<short8v*>(img + base) = h;
  *reinterpret_cast<short8v*>(img + base + 4096) = l;
}

__global__ void init_out_kernel(float* __restrict__ out, const float* __restrict__ p3b, int n) {
  int id = blockIdx.x * 256 + threadIdx.x;
  if (id < n) out[id] = p3b[0];
}

// ---------------- GEMM ----------------
// EPI: 0 relu+bias -> image | 1 relu+bias+residual -> image |
//      2 fused P2 relu + P3 dot -> score | 3 bias, no relu -> UV rows |
//      4 no bias, no relu -> UV rows (in-place safe, full width)
// GATHER: A built in-stage as relu(U[s]+V[d]) from hi/lo UV rows.
// WN: wave-columns (2 -> 128-col block, 256 thr; 8 -> 512-col block, 1024 thr).
template <int EPI, bool GATHER, int WN>
__global__ __launch_bounds__(WN * 128, 4) void gemm4(
    const short* A, const short* A2, const short* __restrict__ B,
    const float* __restrict__ bias, const float* __restrict__ p3,
    const int* __restrict__ isrc, const int* __restrict__ idst,
    short* C, float* __restrict__ score, int M, int yb, int nys) {
  constexpr int BSH = 4096 * WN;            // B lds shorts (8192 / 32768)
  constexpr int BSTR = 512 * WN;            // B slab stride (1024 / 4096)
  constexpr int BPL = 2048 * WN;            // B plane stride (4096 / 16384)
  __shared__ __align__(16) short lds[8192 + BSH];

  const int tid = threadIdx.x;
  const int lane = tid & 63, wid = tid >> 6;
  const int wr = (WN == 2) ? (wid >> 1) : (wid >> 3);
  const int wc = (WN == 2) ? (wid & 1) : (wid & 7);
  const int l15 = lane & 15, lh = lane >> 4;

  // XCD swizzle: 4 x-siblings of a y share (g mod 8) -> same XCD; y streams per XCD
  const int g = blockIdx.x;
  const int xcd = g & 7, rr_ = g >> 3;
  const int x = (WN == 2) ? (rr_ & 3) : 0;
  const int slot = (WN == 2) ? (rr_ >> 2) : rr_;
  const int y = xcd * nys + slot;
  if (y >= yb) return;
  const int m0 = y << 7;
  const int n0 = x << 7;

  const size_t aBase0 = (size_t)y * 16 * 8192;

  int urow = 0, vrow = 0;
  if constexpr (GATHER) {
    int e = m0 + (tid >> 1); if (e > M - 1) e = M - 1;
    urow = isrc[e]; vrow = idst[e];
  }

  auto stage = [&](int kt) {
    const short* ab = A + aBase0 + (size_t)kt * 8192;
    const short* bb = B + (size_t)((WN == 2) ? (x * 16 + kt) : kt) * BSH;
    if constexpr (WN == 2) {
#pragma unroll
      for (int p = 0; p < 4; ++p) gload_lds16(ab + p * 2048 + tid * 8, lds + p * 2048 + tid * 8);
#pragma unroll
      for (int p = 0; p < 4; ++p) gload_lds16(bb + p * 2048 + tid * 8, lds + 8192 + p * 2048 + tid * 8);
    } else {
      gload_lds16(ab + tid * 8, lds + tid * 8);
#pragma unroll
      for (int p = 0; p < 4; ++p) gload_lds16(bb + p * 8192 + tid * 8, lds + 8192 + p * 8192 + tid * 8);
    }
  };

  auto stageG = [&](int kt) {
    const short* bb = B + (size_t)(x * 16 + kt) * 8192;
#pragma unroll
    for (int p = 0; p < 4; ++p) gload_lds16(bb + p * 2048 + tid * 8, lds + 8192 + p * 2048 + tid * 8);
    const int kh = tid & 1;
    const size_t ub = (size_t)(urow >> 7) * 131072 + (urow & 127) * 1024 + kt * 32 + kh * 16;
    const size_t vb = (size_t)(vrow >> 7) * 131072 + (vrow & 127) * 1024 + kt * 32 + kh * 16;
    short8v uh0 = *(const short8v*)(A + ub),        uh1 = *(const short8v*)(A + ub + 8);
    short8v ul0 = *(const short8v*)(A + ub + 512),  ul1 = *(const short8v*)(A + ub + 520);
    short8v vh0 = *(const short8v*)(A2 + vb),       vh1 = *(const short8v*)(A2 + vb + 8);
    short8v vl0 = *(const short8v*)(A2 + vb + 512), vl1 = *(const short8v*)(A2 + vb + 520);
    short8v zh0, zh1, zl0, zl1;
#pragma unroll
    for (int q = 0; q < 8; ++q) {
      float u0 = bf2f((unsigned short)uh0[q]) + bf2f((unsigned short)ul0[q]);
      float v0 = bf2f((unsigned short)vh0[q]) + bf2f((unsigned short)vl0[q]);
      float z0 = fmaxf(u0 + v0, 0.f);
      unsigned zb0 = __float_as_uint(z0);
      zh0[q] = (short)(zb0 >> 16);
      zl0[q] = (short)f2bf_rne(z0 - __uint_as_float(zb0 & 0xffff0000u));
      float u1 = bf2f((unsigned short)uh1[q]) + bf2f((unsigned short)ul1[q]);
      float v1 = bf2f((unsigned short)vh1[q]) + bf2f((unsigned short)vl1[q]);
      float z1 = fmaxf(u1 + v1, 0.f);
      unsigned zb1 = __float_as_uint(z1);
      zh1[q] = (short)(zb1 >> 16);
      zl1[q] = (short)f2bf_rne(z1 - __uint_as_float(zb1 & 0xffff0000u));
    }
    const int da = kh * 2048 + (tid >> 1) * 8;   // [s=2kh][r][8], s-stride 1024
    *reinterpret_cast<short8v*>(lds + da) = zh0;
    *reinterpret_cast<short8v*>(lds + da + 1024) = zh1;
    *reinterpret_cast<short8v*>(lds + 4096 + da) = zl0;
    *reinterpret_cast<short8v*>(lds + 4096 + da + 1024) = zl1;
  };

  f32x4 acc[4][4];
#pragma unroll
  for (int i = 0; i < 4; ++i)
#pragma unroll
    for (int j = 0; j < 4; ++j)
#pragma unroll
      for (int r = 0; r < 4; ++r) acc[i][j][r] = 0.f;

  auto compute = [&]() {
    bf16x8 ah[4], al[4];
#pragma unroll
    for (int i = 0; i < 4; ++i) {
      const int ro = lh * 1024 + (wr * 64 + i * 16 + l15) * 8;
      ah[i] = *reinterpret_cast<const bf16x8*>(lds + ro);
      al[i] = *reinterpret_cast<const bf16x8*>(lds + 4096 + ro);
    }
#pragma unroll
    for (int j = 0; j < 4; ++j) {
      const int co = 8192 + lh * BSTR + (wc * 64 + j * 16 + l15) * 8;
      bf16x8 bh = *reinterpret_cast<const bf16x8*>(lds + co);
      bf16x8 bl = *reinterpret_cast<const bf16x8*>(lds + co + BPL);
#pragma unroll
      for (int i = 0; i < 4; ++i) {
        acc[i][j] = __builtin_amdgcn_mfma_f32_16x16x32_bf16(ah[i], bh, acc[i][j], 0, 0, 0);
        acc[i][j] = __builtin_amdgcn_mfma_f32_16x16x32_bf16(ah[i], bl, acc[i][j], 0, 0, 0);
        acc[i][j] = __builtin_amdgcn_mfma_f32_16x16x32_bf16(al[i], bh, acc[i][j], 0, 0, 0);
      }
    }
  };

  // K-loop: single buffer, 2 barriers per step (m97 structure, 4 blocks/CU overlap)
  for (int kt = 0; kt < 16; ++kt) {
    if (kt) __syncthreads();
    if constexpr (GATHER) stageG(kt); else stage(kt);
    __syncthreads();
    compute();
  }

  // ---------------- epilogue ----------------
  float bj[4], pj[4];
#pragma unroll
  for (int j = 0; j < 4; ++j) {
    const int col = n0 + wc * 64 + j * 16 + l15;
    bj[j] = (EPI == 4) ? 0.f : bias[col];
    pj[j] = (EPI == 2) ? p3[col] : 0.f;
  }

  if constexpr (EPI == 2) {
#pragma unroll
    for (int fi = 0; fi < 4; ++fi)
#pragma unroll
      for (int r = 0; r < 4; ++r) {
        float pS = 0.f;
#pragma unroll
        for (int fj = 0; fj < 4; ++fj)
          pS += fmaxf(acc[fi][fj][r] + bj[fj], 0.f) * pj[fj];
        pS += __shfl_xor(pS, 1);
        pS += __shfl_xor(pS, 2);
        pS += __shfl_xor(pS, 4);
        pS += __shfl_xor(pS, 8);
        const int row = m0 + wr * 64 + fi * 16 + lh * 4 + r;
        if (l15 == 0 && row < M) atomicAdd(&score[row], pS);
      }
  } else {
#pragma unroll
    for (int fi = 0; fi < 4; ++fi)
#pragma unroll
      for (int fj = 0; fj < 4; ++fj) {
        const int col = n0 + wc * 64 + fj * 16 + l15;
#pragma unroll
        for (int r = 0; r < 4; ++r) {
          const int row = m0 + wr * 64 + fi * 16 + lh * 4 + r;
          if (row >= M) continue;
          float v = acc[fi][fj][r] + bj[fj];
          if constexpr (EPI == 0 || EPI == 1) v = fmaxf(v, 0.f);
          if constexpr (EPI == 0 || EPI == 1) {
            const size_t ix = ((size_t)(y * 16 + (col >> 5)) * 2) * 4096 +
                              ((col >> 3) & 3) * 1024 + (row & 127) * 8 + (col & 7);
            // residual source: same image layout, same global index as the C-write
            if constexpr (EPI == 1)
              v += bf2f((unsigned short)A[ix]) + bf2f((unsigned short)A[ix + 4096]);
            unsigned short h = f2bf_rne(v);
            C[ix] = (short)h;
            C[ix + 4096] = (short)f2bf_rne(v - bf2f(h));
          } else {  // EPI 3/4: UV row layout [rb][r][hi512|lo512]
            const size_t ux = (size_t)y * 131072 + (row & 127) * 1024 + col;
            unsigned short h = f2bf_rne(v);
            C[ux] = (short)h;
            C[ux + 512] = (short)f2bf_rne(v - bf2f(h));
          }
        }
      }
  }
}

extern "C" void kernel_launch(void* const* d_in, const int* in_sizes, int n_in,
                              void* d_out, int out_size, void* d_ws, size_t ws_size,
                              hipStream_t stream) {
  (void)n_in; (void)out_size; (void)ws_size;
  const float* x      = (const float*)d_in[0];
  const int* pos_src  = (const int*)d_in[1];
  const int* pos_dst  = (const int*)d_in[2];
  const int* neg_src  = (const int*)d_in[3];
  const int* neg_dst  = (const int*)d_in[4];
  const float* W1 = (const float*)d_in[5];
  const float* b1 = (const float*)d_in[6];
  const float* W2 = (const float*)d_in[7];
  const float* b2 = (const float*)d_in[8];
  const float* Wo = (const float*)d_in[9];
  const float* bo = (const float*)d_in[10];
  const float* P1w = (const float*)d_in[11];
  const float* P1b = (const float*)d_in[12];
  const float* P2w = (const float*)d_in[13];
  const float* P2b = (const float*)d_in[14];
  const float* P3w = (const float*)d_in[15];
  const float* P3b = (const float*)d_in[16];

  const int NN = in_sizes[0] / HID;  // 100000
  const int E = in_sizes[1];         // 100000
  float* out = (float*)d_out;

  const int yb = (NN + 127) / 128;           // 782 (== (E+127)/128)
  const int nys = (yb + 7) / 8;              // 98
  const size_t IMG = (size_t)yb * 131072;    // shorts per activation buffer

  short* A0 = (short*)d_ws;                  // x-img -> h2-img -> U (UV rows)
  short* A1 = A0 + IMG;                      // h1-img -> H-img -> V (UV rows, in place)
  short* wp = A1 + IMG;
  short* Wp1  = wp; wp += 524288;
  short* Wp2  = wp; wp += 524288;
  short* Wpo  = wp; wp += 524288;
  short* Wp2p = wp; wp += 524288;
  short* WpU  = wp; wp += 524288;            // P1 top (xb4 images)
  short* WpV  = wp; wp += 524288;            // P1 bottom (wide image)

  pack4<<<2048, 256, 0, stream>>>(W1, Wp1);
  pack4<<<2048, 256, 0, stream>>>(W2, Wp2);
  pack4<<<2048, 256, 0, stream>>>(Wo, Wpo);
  pack4<<<2048, 256, 0, stream>>>(P2w, Wp2p);
  pack4<<<2048, 256, 0, stream>>>(P1w, WpU);
  packW<<<2048, 256, 0, stream>>>(P1w, WpV);
  const int totX = yb * 128 * 64;
  split_x_img<<<(totX + 255) / 256, 256, 0, stream>>>(x, A0, NN, totX);
  init_out_kernel<<<(2 * E + 255) / 256, 256, 0, stream>>>(out, P3b, 2 * E);

  dim3 g4(8 * nys * 4), gW(8 * nys), b256(256), b1024(1024);

  // encoder: h1 = relu(x@W1+b1); h2 = relu(h1@W2+b2)+h1; H = relu(h2@Wo+bo)+h2
  gemm4<0, false, 2><<<g4, b256, 0, stream>>>(A0, nullptr, Wp1, b1, nullptr, nullptr, nullptr, A1, nullptr, NN, yb, nys);
  gemm4<1, false, 2><<<g4, b256, 0, stream>>>(A1, nullptr, Wp2, b2, nullptr, nullptr, nullptr, A0, nullptr, NN, yb, nys);
  gemm4<1, false, 2><<<g4, b256, 0, stream>>>(A0, nullptr, Wpo, bo, nullptr, nullptr, nullptr, A1, nullptr, NN, yb, nys);

  // U = H@P1top + P1b -> A0 (UV rows); V = H@P1bot -> A1 (UV rows, in place, full width)
  gemm4<3, false, 2><<<g4, b256, 0, stream>>>(A1, nullptr, WpU, P1b, nullptr, nullptr, nullptr, A0, nullptr, NN, yb, nys);
  gemm4<4, false, 8><<<gW, b1024, 0, stream>>>(A1, nullptr, WpV, nullptr, nullptr, nullptr, nullptr, A1, nullptr, NN, yb, nys);

  // edges: z1 = relu(U[s]+V[d]) built in-stage; scores = relu(z1@P2+b)@P3 + b3
  gemm4<2, true, 2><<<g4, b256, 0, stream>>>(A0, A1, Wp2p, P2b, P3w, pos_src, pos_dst, nullptr, out, E, yb, nys);
  gemm4<2, true, 2><<<g4, b256, 0, stream>>>(A0, A1, Wp2p, P2b, P3w, neg_src, neg_dst, nullptr, out + E, E, yb, nys);
}